// Round 5
// baseline (172.257 us; speedup 1.0000x reference)
//
#include <hip/hip_runtime.h>

#define HH 512
#define WW 512
#define HW (HH*WW)
#define EPV 1e-20f

// Box window for center (y,x): rows y-3..y+4, cols x-3..x+4, zero-padded.
// 4 cols/lane (float4). Horizontal windows via prefix/suffix exchange:
//   winC(u) = sum_{d=-3..+4} v(u+d)  (centered, 7 bp)  -- mean window
//   winR(u) = sum_{d=1..8}  v(u+d)  (right,    5 bp)  -- box for out col x0+u
// Vertical = sliding sum with RE-LOADED subtract row (R13): the depth-8
// product ring (128 VGPRs) forced scratch spill (VGPR_Count 168 < ~270 live
// -> ~6000cy/step serialized scratch traffic, the R12 wall). Row c-8 is
// L1/L2-hot, so re-load + re-multiply costs 5 L2-hit loads/step and frees
// the registers. __launch_bounds__(64,2) caps at 256 VGPR, no spill.
// Keeps: XCD-chunked swizzle, winR-at-emit, 2-slack psi ping-pong,
// barrier-free, psi-row fix.
// R14 = R13 resubmitted verbatim (R13 bench was an infra failure).

__device__ __forceinline__ float bpl(int addr, float v) {
    return __int_as_float(__builtin_amdgcn_ds_bpermute(addr, __float_as_int(v)));
}
__device__ __forceinline__ int rcl(int r) { return min(max(r, 0), HH - 1); }

// centered window over strip cols u=4*lane+e
__device__ __forceinline__ float4 winC(float4 v, int aL1, int aR1) {
    float pre2 = v.x + v.y, pre3 = pre2 + v.z, g = pre3 + v.w;
    float suf2 = v.z + v.w, suf3 = v.y + suf2;
    float Ls1 = bpl(aL1, v.w), Ls2 = bpl(aL1, suf2), Ls3 = bpl(aL1, suf3);
    float Rp1 = bpl(aR1, v.x), Rp2 = bpl(aR1, pre2), Rp3 = bpl(aR1, pre3);
    float Rg  = bpl(aR1, g);
    return make_float4(Ls3 + g + Rp1, Ls2 + g + Rp2, Ls1 + g + Rp3, g + Rg);
}
// right-leaning window (serves output col x0+u)
__device__ __forceinline__ float4 winR(float4 v, int aR1, int aR2) {
    float pre2 = v.x + v.y, pre3 = pre2 + v.z, g = pre3 + v.w;
    float suf2 = v.z + v.w, suf3 = v.y + suf2;
    float G1 = bpl(aR1, g);
    float P1 = bpl(aR2, v.x), P2 = bpl(aR2, pre2), P3 = bpl(aR2, pre3);
    float G2 = bpl(aR2, g);
    return make_float4(suf3 + G1 + P1, suf2 + G1 + P2, v.w + G1 + P3, G1 + G2);
}

// ---------------- prep: raw image -> centered (ac) + 1/sqrt(var box) ------
// One wave per (z, strip, 32-row seg). Strips x0 = {0,232,468}. 48 steps
// (rolled 6x8). Vertical-first for the variance path. FIFO depth 4.
__global__ __launch_bounds__(64, 2) void prep_f4(
    const float* __restrict__ outs, const float* __restrict__ labs,
    float* __restrict__ ac, float* __restrict__ rs, float* __restrict__ outbuf)
{
    const int l  = threadIdx.x;
    if (blockIdx.x == 0 && blockIdx.y == 0 && blockIdx.z == 0 && l < 25)
        outbuf[l] = 0.f;                      // replaces hipMemsetAsync
    const int s  = blockIdx.x;
    const int x0 = (s == 0) ? 0 : (s == 1 ? 232 : 468);
    const int y0 = 32 * blockIdx.y;
    const int z  = blockIdx.z;

    const float* src = (z < 24) ? outs + z * HW : labs + (z - 24) * HW;
    float* acd = ac + z * HW;
    float* rsd = rs + z * HW;

    const int   bcol0 = x0 - 4 + 4 * l;
    const int   bcol  = min(max(bcol0, 0), WW - 4);
    const float cmask = (bcol0 >= 0 && bcol0 <= WW - 4) ? 1.f : 0.f;
    const int   ocol0 = x0 + 4 * l;
    const int   aL1 = ((l - 1) & 63) << 2;
    const int   aR1 = ((l + 1) & 63) << 2;
    const int   aR2 = ((l + 2) & 63) << 2;
    const bool stA = (l >= 1 && l <= 60 && bcol0 >= 0 && bcol0 <= WW - 4);
    const bool stS = (l >= ((x0 == 0) ? 0 : 1) && l <= 59 && ocol0 <= WW - 4);

    float4 fifo[4];
    fifo[0] = *(const float4*)&src[rcl(y0 - 7) * WW + bcol];
    fifo[1] = *(const float4*)&src[rcl(y0 - 6) * WW + bcol];
    fifo[2] = *(const float4*)&src[rcl(y0 - 5) * WW + bcol];
    fifo[3] = *(const float4*)&src[rcl(y0 - 4) * WW + bcol];

    float4 araw[4], haR[8], rgS[8];
    float4 VA = make_float4(0,0,0,0), Vq = make_float4(0,0,0,0);
    #pragma unroll
    for (int k = 0; k < 4; ++k) araw[k] = make_float4(0,0,0,0);
    #pragma unroll
    for (int k = 0; k < 8; ++k) { haR[k] = make_float4(0,0,0,0); rgS[k] = make_float4(0,0,0,0); }

    auto step = [&](const int t, const int kk) {
        const int   r  = y0 - 7 + t;
        const float rm = (r >= 0 && r < HH) ? cmask : 0.f;
        float4 raw = fifo[kk & 3];
        float4 av  = make_float4(raw.x*rm, raw.y*rm, raw.z*rm, raw.w*rm);
        if (t <= 43) fifo[kk & 3] = *(const float4*)&src[rcl(r + 4) * WW + bcol];

        float4 h = winC(av, aL1, aR1);
        VA.x += h.x - haR[kk].x; VA.y += h.y - haR[kk].y;
        VA.z += h.z - haR[kk].z; VA.w += h.w - haR[kk].w;
        haR[kk] = h;

        float4 aold = araw[kk & 3]; araw[kk & 3] = av;   // row c = r-4
        const int   c  = r - 4;
        const float cm = (c >= 0 && c < HH) ? cmask : 0.f;
        float4 acv = make_float4((aold.x - VA.x*(1.f/64.f))*cm,
                                 (aold.y - VA.y*(1.f/64.f))*cm,
                                 (aold.z - VA.z*(1.f/64.f))*cm,
                                 (aold.w - VA.w*(1.f/64.f))*cm);
        if (t >= 11 && t <= 42) {
            if (stA) *(float4*)&acd[c * WW + bcol0] = acv;
        }
        float4 sq = make_float4(acv.x*acv.x, acv.y*acv.y, acv.z*acv.z, acv.w*acv.w);
        Vq.x += sq.x - rgS[kk].x; Vq.y += sq.y - rgS[kk].y;
        Vq.z += sq.z - rgS[kk].z; Vq.w += sq.w - rgS[kk].w;
        rgS[kk] = sq;
        if (t >= 15 && t <= 46) {                        // emit row y = c-4
            const int y = c - 4;                         // y in [y0, y0+31]
            float4 h2 = winR(Vq, aR1, aR2);              // box sum of sq
            if (stS) *(float4*)&rsd[y * WW + ocol0] = make_float4(
                __frsqrt_rn(fmaxf(h2.x, EPV)), __frsqrt_rn(fmaxf(h2.y, EPV)),
                __frsqrt_rn(fmaxf(h2.z, EPV)), __frsqrt_rn(fmaxf(h2.w, EPV)));
        }
    };
    for (int it = 0; it < 6; ++it) {
        const int t0 = it * 8;
        #pragma unroll
        for (int kk = 0; kk < 8; ++kk) step(t0 + kk, kk);
    }
}

// ---------------- main: product boxes, ring-free sliding sums -------------
// One wave per (z=b*6+i, strip x0={0,240,480}, 19-row seg). 26 steps.
// 1944 waves, XCD-chunked: XCD k owns z in {3k,3k+1,3k+2}.
// Vp[j] += p(row c) - p(row c-8); the subtract row is RE-LOADED (L2-hot)
// through a second 2-slack fifo instead of kept in a register ring.
__global__ __launch_bounds__(64, 2) void ncc_f4(
    const float* __restrict__ ac, const float* __restrict__ rs,
    float* __restrict__ out)
{
    const int l   = threadIdx.x;
    const int n   = blockIdx.x;            // 0..1943
    const int xcd = n & 7;                 // block n -> XCD n%8 (round-robin)
    const int p   = n >> 3;                // 0..242 within XCD
    const int zq  = p / 81;                // 0..2
    const int rem = p - 81 * zq;           // 0..80
    const int seg = rem / 3;               // 0..26
    const int stp = rem - 3 * seg;         // 0..2
    const int x0  = 240 * stp;
    const int y0  = 19 * seg;
    const int z   = 3 * xcd + zq;          // b*6 + i
    const int b   = z / 6;

    const float* acp = ac + z * HW;
    const float* sip = rs + z * HW;
    const float* bcp[4]; const float* sjp[4];
    #pragma unroll
    for (int j = 0; j < 4; ++j) {
        bcp[j] = ac + (24 + b * 4 + j) * HW;
        sjp[j] = rs + (24 + b * 4 + j) * HW;
    }

    const int   bcol0 = x0 - 4 + 4 * l;
    const int   bcol  = min(max(bcol0, 0), WW - 4);
    const float cmask = (bcol0 >= 0 && bcol0 <= WW - 4) ? 1.f : 0.f;
    const int   ocol0 = x0 + 4 * l;
    const int   ocol  = min(ocol0, WW - 4);
    const float om    = (l <= 59 && ocol0 <= WW - 4) ? 1.f : 0.f;
    const int   aR1 = ((l + 1) & 63) << 2;
    const int   aR2 = ((l + 2) & 63) << 2;

    float4 fa[2], fb[4][2];      // "new" rows (add,    2-step slack)
    float4 faO[2], fbO[4][2];    // "old" rows (subtract, 2-step slack)
    {
        const int r0 = rcl(y0 - 3), r1 = rcl(y0 - 2);
        fa[0]  = *(const float4*)&acp[r0 * WW + bcol];
        fa[1]  = *(const float4*)&acp[r1 * WW + bcol];
        faO[0] = *(const float4*)&acp[r0 * WW + bcol];
        faO[1] = *(const float4*)&acp[r1 * WW + bcol];
        #pragma unroll
        for (int j = 0; j < 4; ++j) {
            fb[j][0]  = *(const float4*)&bcp[j][r0 * WW + bcol];
            fb[j][1]  = *(const float4*)&bcp[j][r1 * WW + bcol];
            fbO[j][0] = *(const float4*)&bcp[j][r0 * WW + bcol];
            fbO[j][1] = *(const float4*)&bcp[j][r1 * WW + bcol];
        }
    }

    float4 Vp[4];
    float4 psiB[2], psjB[2][4];
    float4 xs = make_float4(0,0,0,0);
    #pragma unroll
    for (int j = 0; j < 4; ++j) Vp[j] = make_float4(0,0,0,0);
    #pragma unroll
    for (int q = 0; q < 2; ++q) {
        psiB[q] = make_float4(0,0,0,0);
        #pragma unroll
        for (int j = 0; j < 4; ++j) psjB[q][j] = make_float4(0,0,0,0);
    }

    auto step = [&](const int t, const int kk) {
        const int   c  = y0 - 3 + t;                 // row being ADDED
        const float rm = (c >= 0 && c < HH) ? cmask : 0.f;
        float4 av = fa[kk & 1];
        av = make_float4(av.x*rm, av.y*rm, av.z*rm, av.w*rm);
        float4 bv0 = fb[0][kk & 1], bv1 = fb[1][kk & 1];
        float4 bv2 = fb[2][kk & 1], bv3 = fb[3][kk & 1];
        if (t <= 23) {
            const int rn = rcl(c + 2);
            fa[kk & 1] = *(const float4*)&acp[rn * WW + bcol];
            #pragma unroll
            for (int j = 0; j < 4; ++j)
                fb[j][kk & 1] = *(const float4*)&bcp[j][rn * WW + bcol];
        }
        // add new products
        Vp[0].x += av.x*bv0.x; Vp[0].y += av.y*bv0.y; Vp[0].z += av.z*bv0.z; Vp[0].w += av.w*bv0.w;
        Vp[1].x += av.x*bv1.x; Vp[1].y += av.y*bv1.y; Vp[1].z += av.z*bv1.z; Vp[1].w += av.w*bv1.w;
        Vp[2].x += av.x*bv2.x; Vp[2].y += av.y*bv2.y; Vp[2].z += av.z*bv2.z; Vp[2].w += av.w*bv2.w;
        Vp[3].x += av.x*bv3.x; Vp[3].y += av.y*bv3.y; Vp[3].z += av.z*bv3.z; Vp[3].w += av.w*bv3.w;
        // subtract row c-8 (re-loaded; L2-hot from 8 steps ago)
        if (t >= 8) {
            const int   co  = c - 8;                 // >= y0-3, < HH always
            const float rmO = (co >= 0) ? cmask : 0.f;
            float4 avO = faO[kk & 1];
            avO = make_float4(avO.x*rmO, avO.y*rmO, avO.z*rmO, avO.w*rmO);
            float4 bo0 = fbO[0][kk & 1], bo1 = fbO[1][kk & 1];
            float4 bo2 = fbO[2][kk & 1], bo3 = fbO[3][kk & 1];
            if (t <= 23) {
                const int ro = rcl(c - 6);
                faO[kk & 1] = *(const float4*)&acp[ro * WW + bcol];
                #pragma unroll
                for (int j = 0; j < 4; ++j)
                    fbO[j][kk & 1] = *(const float4*)&bcp[j][ro * WW + bcol];
            }
            Vp[0].x -= avO.x*bo0.x; Vp[0].y -= avO.y*bo0.y; Vp[0].z -= avO.z*bo0.z; Vp[0].w -= avO.w*bo0.w;
            Vp[1].x -= avO.x*bo1.x; Vp[1].y -= avO.y*bo1.y; Vp[1].z -= avO.z*bo1.z; Vp[1].w -= avO.w*bo1.w;
            Vp[2].x -= avO.x*bo2.x; Vp[2].y -= avO.y*bo2.y; Vp[2].z -= avO.z*bo2.z; Vp[2].w -= avO.w*bo2.w;
            Vp[3].x -= avO.x*bo3.x; Vp[3].y -= avO.y*bo3.y; Vp[3].z -= avO.z*bo3.z; Vp[3].w -= avO.w*bo3.w;
        }

        if (t >= 7) {
            // emit row y = y0+t-7; psiB[t&1] holds row y (loaded 2 steps ago)
            const int   y  = y0 + t - 7;
            const float em = (y < HH) ? om : 0.f;
            const float4 psi = psiB[t & 1];
            float mmx = -1.f, mmy = -1.f, mmz = -1.f, mmw = -1.f;
            #pragma unroll
            for (int j = 0; j < 4; ++j) {
                float4 hj = winR(Vp[j], aR1, aR2);
                float4 sj = psjB[t & 1][j];
                mmx = fmaxf(mmx, hj.x * (psi.x * sj.x));
                mmy = fmaxf(mmy, hj.y * (psi.y * sj.y));
                mmz = fmaxf(mmz, hj.z * (psi.z * sj.z));
                mmw = fmaxf(mmw, hj.w * (psi.w * sj.w));
            }
            xs.x += em * (1.f - fminf(mmx, 1.f));
            xs.y += em * (1.f - fminf(mmy, 1.f));
            xs.z += em * (1.f - fminf(mmz, 1.f));
            xs.w += em * (1.f - fminf(mmw, 1.f));
        }
        if (t >= 5 && t <= 23) {             // prefetch row y(t+2), 2-step slack
            const int yn = min(y0 + t - 5, HH - 1);
            psiB[t & 1] = *(const float4*)&sip[yn * WW + ocol];
            #pragma unroll
            for (int j = 0; j < 4; ++j)
                psjB[t & 1][j] = *(const float4*)&sjp[j][yn * WW + ocol];
        }
    };
    for (int it = 0; it < 3; ++it) {
        const int t0 = it * 8;
        #pragma unroll
        for (int kk = 0; kk < 8; ++kk) step(t0 + kk, kk);
    }
    step(24, 0); step(25, 1);

    float xt = xs.x + xs.y + xs.z + xs.w;
    #pragma unroll
    for (int off = 32; off > 0; off >>= 1) xt += __shfl_down(xt, off);
    if (l == 0) {
        atomicAdd(&out[1 + z], xt * (1.f / (float)HW));
        atomicAdd(&out[0],     xt * (1.f / (24.f * (float)HW)));
    }
}

extern "C" void kernel_launch(void* const* d_in, const int* in_sizes, int n_in,
                              void* d_out, int out_size, void* d_ws, size_t ws_size,
                              hipStream_t stream) {
    const float* outs = (const float*)d_in[0];   // (4,6,512,512)
    const float* labs = (const float*)d_in[1];   // (4,4,512,512)
    float* out = (float*)d_out;                  // 25 floats
    float* ws  = (float*)d_ws;

    float* acw = ws;                 // 40*HW (a:0..23, b:24..39)
    float* rsw = ws + 40 * HW;       // 40*HW  (1/sqrt of variance box)

    // prep: 3 strips x 16 segs(32 rows) x 40 images (also zeroes out)
    prep_f4<<<dim3(3, 16, 40), 64, 0, stream>>>(outs, labs, acw, rsw, out);
    // main: 1944 blocks, XCD-chunked decode inside the kernel
    ncc_f4<<<dim3(1944, 1, 1), 64, 0, stream>>>(acw, rsw, out);
}

// Round 6
// 151.885 us; speedup vs baseline: 1.1341x; 1.1341x over previous
//
#include <hip/hip_runtime.h>

#define HH 512
#define WW 512
#define HW (HH*WW)
#define EPV 1e-20f

// Box window for center (y,x): rows y-3..y+4, cols x-3..x+4, zero-padded.
// 4 cols/lane (float4). Horizontal windows via prefix/suffix exchange:
//   winC(u) = sum_{d=-3..+4} v(u+d)  (centered, 7 bp)  -- mean window
//   winR(u) = sum_{d=1..8}  v(u+d)  (right,    5 bp)  -- box for out col x0+u
// Vertical = sliding sum; subtract row re-loaded (L2-hot), no register ring.
// R15: TLP scale-out. Evidence: three structurally different kernels all
// ~69-80us with VALUBusy 12-16%, occ ~14%, and warm-replay (FETCH 124KB)
// still 69us -> latency-bound with ~1.9 waves/SIMD. ncc segs 19->8 rows
// (4608 waves, 18/CU resident at VGPR=100), prep segs 32->16 (3840 waves).
// Atomic-tail fix: per-z partials at 256B stride + tiny finalize kernel
// (old code serialized ~2*nblocks RMWs on ONE cache line).
// Keeps: XCD-chunked swizzle, winR-at-emit, 2-slack psi ping-pong,
// barrier-free, psi-row fix, launch_bounds(64,2).

__device__ __forceinline__ float bpl(int addr, float v) {
    return __int_as_float(__builtin_amdgcn_ds_bpermute(addr, __float_as_int(v)));
}
__device__ __forceinline__ int rcl(int r) { return min(max(r, 0), HH - 1); }

// centered window over strip cols u=4*lane+e
__device__ __forceinline__ float4 winC(float4 v, int aL1, int aR1) {
    float pre2 = v.x + v.y, pre3 = pre2 + v.z, g = pre3 + v.w;
    float suf2 = v.z + v.w, suf3 = v.y + suf2;
    float Ls1 = bpl(aL1, v.w), Ls2 = bpl(aL1, suf2), Ls3 = bpl(aL1, suf3);
    float Rp1 = bpl(aR1, v.x), Rp2 = bpl(aR1, pre2), Rp3 = bpl(aR1, pre3);
    float Rg  = bpl(aR1, g);
    return make_float4(Ls3 + g + Rp1, Ls2 + g + Rp2, Ls1 + g + Rp3, g + Rg);
}
// right-leaning window (serves output col x0+u)
__device__ __forceinline__ float4 winR(float4 v, int aR1, int aR2) {
    float pre2 = v.x + v.y, pre3 = pre2 + v.z, g = pre3 + v.w;
    float suf2 = v.z + v.w, suf3 = v.y + suf2;
    float G1 = bpl(aR1, g);
    float P1 = bpl(aR2, v.x), P2 = bpl(aR2, pre2), P3 = bpl(aR2, pre3);
    float G2 = bpl(aR2, g);
    return make_float4(suf3 + G1 + P1, suf2 + G1 + P2, v.w + G1 + P3, G1 + G2);
}

// ---------------- prep: raw image -> centered (ac) + 1/sqrt(var box) ------
// One wave per (z, strip, 16-row seg). Strips x0 = {0,232,468}. 32 steps
// (rolled 4x8; t=31 is a guarded no-op). FIFO depth 4.
__global__ __launch_bounds__(64, 2) void prep_f4(
    const float* __restrict__ outs, const float* __restrict__ labs,
    float* __restrict__ ac, float* __restrict__ rs, float* __restrict__ wsum)
{
    const int l  = threadIdx.x;
    if (blockIdx.x == 0 && blockIdx.y == 0 && blockIdx.z == 0 && l < 24)
        wsum[l * 64] = 0.f;                   // zero per-z partial slots
    const int s  = blockIdx.x;
    const int x0 = (s == 0) ? 0 : (s == 1 ? 232 : 468);
    const int y0 = 16 * blockIdx.y;
    const int z  = blockIdx.z;

    const float* src = (z < 24) ? outs + z * HW : labs + (z - 24) * HW;
    float* acd = ac + z * HW;
    float* rsd = rs + z * HW;

    const int   bcol0 = x0 - 4 + 4 * l;
    const int   bcol  = min(max(bcol0, 0), WW - 4);
    const float cmask = (bcol0 >= 0 && bcol0 <= WW - 4) ? 1.f : 0.f;
    const int   ocol0 = x0 + 4 * l;
    const int   aL1 = ((l - 1) & 63) << 2;
    const int   aR1 = ((l + 1) & 63) << 2;
    const int   aR2 = ((l + 2) & 63) << 2;
    const bool stA = (l >= 1 && l <= 60 && bcol0 >= 0 && bcol0 <= WW - 4);
    const bool stS = (l >= ((x0 == 0) ? 0 : 1) && l <= 59 && ocol0 <= WW - 4);

    float4 fifo[4];
    fifo[0] = *(const float4*)&src[rcl(y0 - 7) * WW + bcol];
    fifo[1] = *(const float4*)&src[rcl(y0 - 6) * WW + bcol];
    fifo[2] = *(const float4*)&src[rcl(y0 - 5) * WW + bcol];
    fifo[3] = *(const float4*)&src[rcl(y0 - 4) * WW + bcol];

    float4 araw[4], haR[8], rgS[8];
    float4 VA = make_float4(0,0,0,0), Vq = make_float4(0,0,0,0);
    #pragma unroll
    for (int k = 0; k < 4; ++k) araw[k] = make_float4(0,0,0,0);
    #pragma unroll
    for (int k = 0; k < 8; ++k) { haR[k] = make_float4(0,0,0,0); rgS[k] = make_float4(0,0,0,0); }

    auto step = [&](const int t, const int kk) {
        const int   r  = y0 - 7 + t;
        const float rm = (r >= 0 && r < HH) ? cmask : 0.f;
        float4 raw = fifo[kk & 3];
        float4 av  = make_float4(raw.x*rm, raw.y*rm, raw.z*rm, raw.w*rm);
        if (t <= 26) fifo[kk & 3] = *(const float4*)&src[rcl(r + 4) * WW + bcol];

        float4 h = winC(av, aL1, aR1);
        VA.x += h.x - haR[kk].x; VA.y += h.y - haR[kk].y;
        VA.z += h.z - haR[kk].z; VA.w += h.w - haR[kk].w;
        haR[kk] = h;

        float4 aold = araw[kk & 3]; araw[kk & 3] = av;   // row c = r-4
        const int   c  = r - 4;
        const float cm = (c >= 0 && c < HH) ? cmask : 0.f;
        float4 acv = make_float4((aold.x - VA.x*(1.f/64.f))*cm,
                                 (aold.y - VA.y*(1.f/64.f))*cm,
                                 (aold.z - VA.z*(1.f/64.f))*cm,
                                 (aold.w - VA.w*(1.f/64.f))*cm);
        if (t >= 11 && t <= 26) {
            if (stA) *(float4*)&acd[c * WW + bcol0] = acv;   // c in [y0,y0+15]
        }
        float4 sq = make_float4(acv.x*acv.x, acv.y*acv.y, acv.z*acv.z, acv.w*acv.w);
        Vq.x += sq.x - rgS[kk].x; Vq.y += sq.y - rgS[kk].y;
        Vq.z += sq.z - rgS[kk].z; Vq.w += sq.w - rgS[kk].w;
        rgS[kk] = sq;
        if (t >= 15 && t <= 30) {                        // emit row y = c-4
            const int y = c - 4;                         // y in [y0, y0+15]
            float4 h2 = winR(Vq, aR1, aR2);              // box sum of sq
            if (stS) *(float4*)&rsd[y * WW + ocol0] = make_float4(
                __frsqrt_rn(fmaxf(h2.x, EPV)), __frsqrt_rn(fmaxf(h2.y, EPV)),
                __frsqrt_rn(fmaxf(h2.z, EPV)), __frsqrt_rn(fmaxf(h2.w, EPV)));
        }
    };
    for (int it = 0; it < 4; ++it) {
        const int t0 = it * 8;
        #pragma unroll
        for (int kk = 0; kk < 8; ++kk) step(t0 + kk, kk);
    }
}

// ---------------- main: product boxes, ring-free sliding sums -------------
// One wave per (z=b*6+i, strip x0={0,240,480}, 8-row seg). 15 steps, fully
// unrolled (compile-time guards). 4608 waves = 18/CU resident (VGPR=100 ->
// 20/CU capacity). XCD-chunked: XCD k owns z in {3k,3k+1,3k+2}.
// Vp[j] += p(row c) - p(row c-8); subtract row re-loaded (L1/L2-hot).
__global__ __launch_bounds__(64, 2) void ncc_f4(
    const float* __restrict__ ac, const float* __restrict__ rs,
    float* __restrict__ wsum)
{
    const int l   = threadIdx.x;
    const int n   = blockIdx.x;            // 0..4607
    const int xcd = n & 7;                 // block n -> XCD n%8 (round-robin)
    const int p   = n >> 3;                // 0..575 within XCD
    const int zq  = p / 192;               // 0..2
    const int rem = p - 192 * zq;          // 0..191
    const int seg = rem / 3;               // 0..63
    const int stp = rem - 3 * seg;         // 0..2
    const int x0  = 240 * stp;
    const int y0  = 8 * seg;
    const int z   = 3 * xcd + zq;          // b*6 + i
    const int b   = z / 6;

    const float* acp = ac + z * HW;
    const float* sip = rs + z * HW;
    const float* bcp[4]; const float* sjp[4];
    #pragma unroll
    for (int j = 0; j < 4; ++j) {
        bcp[j] = ac + (24 + b * 4 + j) * HW;
        sjp[j] = rs + (24 + b * 4 + j) * HW;
    }

    const int   bcol0 = x0 - 4 + 4 * l;
    const int   bcol  = min(max(bcol0, 0), WW - 4);
    const float cmask = (bcol0 >= 0 && bcol0 <= WW - 4) ? 1.f : 0.f;
    const int   ocol0 = x0 + 4 * l;
    const int   ocol  = min(ocol0, WW - 4);
    const float om    = (l <= 59 && ocol0 <= WW - 4) ? 1.f : 0.f;
    const int   aR1 = ((l + 1) & 63) << 2;
    const int   aR2 = ((l + 2) & 63) << 2;

    float4 fa[2], fb[4][2];      // "new" rows (add,    2-step slack)
    float4 faO[2], fbO[4][2];    // "old" rows (subtract, 2-step slack)
    {
        const int r0 = rcl(y0 - 3), r1 = rcl(y0 - 2);
        fa[0]  = *(const float4*)&acp[r0 * WW + bcol];
        fa[1]  = *(const float4*)&acp[r1 * WW + bcol];
        faO[0] = *(const float4*)&acp[r0 * WW + bcol];
        faO[1] = *(const float4*)&acp[r1 * WW + bcol];
        #pragma unroll
        for (int j = 0; j < 4; ++j) {
            fb[j][0]  = *(const float4*)&bcp[j][r0 * WW + bcol];
            fb[j][1]  = *(const float4*)&bcp[j][r1 * WW + bcol];
            fbO[j][0] = *(const float4*)&bcp[j][r0 * WW + bcol];
            fbO[j][1] = *(const float4*)&bcp[j][r1 * WW + bcol];
        }
    }

    float4 Vp[4];
    float4 psiB[2], psjB[2][4];
    float4 xs = make_float4(0,0,0,0);
    #pragma unroll
    for (int j = 0; j < 4; ++j) Vp[j] = make_float4(0,0,0,0);
    #pragma unroll
    for (int q = 0; q < 2; ++q) {
        psiB[q] = make_float4(0,0,0,0);
        #pragma unroll
        for (int j = 0; j < 4; ++j) psjB[q][j] = make_float4(0,0,0,0);
    }

    auto step = [&](const int t, const int kk) {
        const int   c  = y0 - 3 + t;                 // row being ADDED
        const float rm = (c >= 0 && c < HH) ? cmask : 0.f;
        float4 av = fa[kk & 1];
        av = make_float4(av.x*rm, av.y*rm, av.z*rm, av.w*rm);
        float4 bv0 = fb[0][kk & 1], bv1 = fb[1][kk & 1];
        float4 bv2 = fb[2][kk & 1], bv3 = fb[3][kk & 1];
        if (t <= 12) {                               // consumed through t=14
            const int rn = rcl(c + 2);
            fa[kk & 1] = *(const float4*)&acp[rn * WW + bcol];
            #pragma unroll
            for (int j = 0; j < 4; ++j)
                fb[j][kk & 1] = *(const float4*)&bcp[j][rn * WW + bcol];
        }
        // add new products
        Vp[0].x += av.x*bv0.x; Vp[0].y += av.y*bv0.y; Vp[0].z += av.z*bv0.z; Vp[0].w += av.w*bv0.w;
        Vp[1].x += av.x*bv1.x; Vp[1].y += av.y*bv1.y; Vp[1].z += av.z*bv1.z; Vp[1].w += av.w*bv1.w;
        Vp[2].x += av.x*bv2.x; Vp[2].y += av.y*bv2.y; Vp[2].z += av.z*bv2.z; Vp[2].w += av.w*bv2.w;
        Vp[3].x += av.x*bv3.x; Vp[3].y += av.y*bv3.y; Vp[3].z += av.z*bv3.z; Vp[3].w += av.w*bv3.w;
        // subtract row c-8 (re-loaded; L1/L2-hot from 8 steps ago)
        if (t >= 8) {
            const int   co  = c - 8;
            const float rmO = (co >= 0) ? cmask : 0.f;
            float4 avO = faO[kk & 1];
            avO = make_float4(avO.x*rmO, avO.y*rmO, avO.z*rmO, avO.w*rmO);
            float4 bo0 = fbO[0][kk & 1], bo1 = fbO[1][kk & 1];
            float4 bo2 = fbO[2][kk & 1], bo3 = fbO[3][kk & 1];
            Vp[0].x -= avO.x*bo0.x; Vp[0].y -= avO.y*bo0.y; Vp[0].z -= avO.z*bo0.z; Vp[0].w -= avO.w*bo0.w;
            Vp[1].x -= avO.x*bo1.x; Vp[1].y -= avO.y*bo1.y; Vp[1].z -= avO.z*bo1.z; Vp[1].w -= avO.w*bo1.w;
            Vp[2].x -= avO.x*bo2.x; Vp[2].y -= avO.y*bo2.y; Vp[2].z -= avO.z*bo2.z; Vp[2].w -= avO.w*bo2.w;
            Vp[3].x -= avO.x*bo3.x; Vp[3].y -= avO.y*bo3.y; Vp[3].z -= avO.z*bo3.z; Vp[3].w -= avO.w*bo3.w;
        }
        if (t >= 6 && t <= 12) {                     // subtract-row prefetch
            const int ro = rcl(c - 6);               // used at t+2 (row c-8)
            faO[kk & 1] = *(const float4*)&acp[ro * WW + bcol];
            #pragma unroll
            for (int j = 0; j < 4; ++j)
                fbO[j][kk & 1] = *(const float4*)&bcp[j][ro * WW + bcol];
        }

        if (t >= 7) {
            // emit row y = y0+t-7; psiB[t&1] holds row y (loaded 2 steps ago)
            const int   y  = y0 + t - 7;
            const float em = (y < HH) ? om : 0.f;
            const float4 psi = psiB[t & 1];
            float mmx = -1.f, mmy = -1.f, mmz = -1.f, mmw = -1.f;
            #pragma unroll
            for (int j = 0; j < 4; ++j) {
                float4 hj = winR(Vp[j], aR1, aR2);
                float4 sj = psjB[t & 1][j];
                mmx = fmaxf(mmx, hj.x * (psi.x * sj.x));
                mmy = fmaxf(mmy, hj.y * (psi.y * sj.y));
                mmz = fmaxf(mmz, hj.z * (psi.z * sj.z));
                mmw = fmaxf(mmw, hj.w * (psi.w * sj.w));
            }
            xs.x += em * (1.f - fminf(mmx, 1.f));
            xs.y += em * (1.f - fminf(mmy, 1.f));
            xs.z += em * (1.f - fminf(mmz, 1.f));
            xs.w += em * (1.f - fminf(mmw, 1.f));
        }
        if (t >= 5 && t <= 12) {             // psi prefetch, 2-step slack
            const int yn = min(y0 + t - 5, HH - 1);
            psiB[t & 1] = *(const float4*)&sip[yn * WW + ocol];
            #pragma unroll
            for (int j = 0; j < 4; ++j)
                psjB[t & 1][j] = *(const float4*)&sjp[j][yn * WW + ocol];
        }
    };
    #pragma unroll
    for (int t = 0; t < 15; ++t) step(t, t & 7);

    float xt = xs.x + xs.y + xs.z + xs.w;
    #pragma unroll
    for (int off = 32; off > 0; off >>= 1) xt += __shfl_down(xt, off);
    if (l == 0) atomicAdd(&wsum[z * 64], xt);   // per-z line, 192-way only
}

// ---------------- finalize: 24 partials -> 25 outputs ---------------------
__global__ void fin_f4(const float* __restrict__ wsum, float* __restrict__ out)
{
    const int l = threadIdx.x;
    float v = (l < 24) ? wsum[l * 64] : 0.f;
    if (l < 24) out[1 + l] = v * (1.f / (float)HW);
    #pragma unroll
    for (int off = 32; off > 0; off >>= 1) v += __shfl_down(v, off);
    if (l == 0) out[0] = v * (1.f / (24.f * (float)HW));
}

extern "C" void kernel_launch(void* const* d_in, const int* in_sizes, int n_in,
                              void* d_out, int out_size, void* d_ws, size_t ws_size,
                              hipStream_t stream) {
    const float* outs = (const float*)d_in[0];   // (4,6,512,512)
    const float* labs = (const float*)d_in[1];   // (4,4,512,512)
    float* out = (float*)d_out;                  // 25 floats
    float* ws  = (float*)d_ws;

    float* acw  = ws;                 // 40*HW (a:0..23, b:24..39)
    float* rsw  = ws + 40 * HW;       // 40*HW  (1/sqrt of variance box)
    float* wsum = ws + 80 * HW;       // 24 slots at 64-float (256B) stride

    // prep: 3 strips x 32 segs(16 rows) x 40 images (also zeroes wsum)
    prep_f4<<<dim3(3, 32, 40), 64, 0, stream>>>(outs, labs, acw, rsw, wsum);
    // main: 4608 blocks, XCD-chunked decode inside the kernel
    ncc_f4<<<dim3(4608, 1, 1), 64, 0, stream>>>(acw, rsw, wsum);
    // finalize: one wave
    fin_f4<<<dim3(1, 1, 1), 64, 0, stream>>>(wsum, out);
}

// Round 7
// 123.881 us; speedup vs baseline: 1.3905x; 1.2261x over previous
//
#include <hip/hip_runtime.h>
#include <hip/hip_fp16.h>

#define HH 512
#define WW 512
#define HW (HH*WW)
#define EPV 1e-20f

// Box window for center (y,x): rows y-3..y+4, cols x-3..x+4, zero-padded.
// 4 cols/lane. Horizontal windows via prefix/suffix bpermute exchange:
//   winC(u) = sum_{d=-3..+4} v(u+d)   -- mean window (prep)
//   winR(u) = sum_{d=1..8}  v(u+d)   -- box for out col x0+u
// Vertical = sliding sum; subtract row re-loaded, no register ring.
// R16: fp16 intermediates (ac, rs). Evidence: R15 warm-replay runs 49.5us
// at FETCH=147KB (fully cached) == cold 49.5us at 3.36TB/s -> bound by the
// per-CU L1/TCP data port (15 dwordx4/step/wave = 63K cy/CU = 53% of wall),
// not HBM, not latency alone. fp16 halves bytes/access -> port time halves.
// ac in (-1,1): fp16 err 2^-12, cc err <=0.0005 (Cauchy-Schwarz). rs clamped
// to 60000 pre-pack (no inf; +-blowups absorbed by fmax(-1)/fmin(1) clamps).
// Keeps: XCD-chunked swizzle, winR-at-emit, 2-slack ping-pongs, barrier-free,
// 8-row ncc segs (4608 waves), per-z wsum + fin kernel, launch_bounds(64,2).

__device__ __forceinline__ float bpl(int addr, float v) {
    return __int_as_float(__builtin_amdgcn_ds_bpermute(addr, __float_as_int(v)));
}
__device__ __forceinline__ int rcl(int r) { return min(max(r, 0), HH - 1); }

__device__ __forceinline__ float4 h2f4(uint2 r) {
    __half2 lo = *(__half2*)&r.x, hi = *(__half2*)&r.y;
    float2 a = __half22float2(lo), b = __half22float2(hi);
    return make_float4(a.x, a.y, b.x, b.y);
}
__device__ __forceinline__ uint2 f2h4(float4 v) {
    __half2 lo = __floats2half2_rn(v.x, v.y);
    __half2 hi = __floats2half2_rn(v.z, v.w);
    uint2 r;
    r.x = *(unsigned int*)&lo;
    r.y = *(unsigned int*)&hi;
    return r;
}

// centered window over strip cols u=4*lane+e
__device__ __forceinline__ float4 winC(float4 v, int aL1, int aR1) {
    float pre2 = v.x + v.y, pre3 = pre2 + v.z, g = pre3 + v.w;
    float suf2 = v.z + v.w, suf3 = v.y + suf2;
    float Ls1 = bpl(aL1, v.w), Ls2 = bpl(aL1, suf2), Ls3 = bpl(aL1, suf3);
    float Rp1 = bpl(aR1, v.x), Rp2 = bpl(aR1, pre2), Rp3 = bpl(aR1, pre3);
    float Rg  = bpl(aR1, g);
    return make_float4(Ls3 + g + Rp1, Ls2 + g + Rp2, Ls1 + g + Rp3, g + Rg);
}
// right-leaning window (serves output col x0+u)
__device__ __forceinline__ float4 winR(float4 v, int aR1, int aR2) {
    float pre2 = v.x + v.y, pre3 = pre2 + v.z, g = pre3 + v.w;
    float suf2 = v.z + v.w, suf3 = v.y + suf2;
    float G1 = bpl(aR1, g);
    float P1 = bpl(aR2, v.x), P2 = bpl(aR2, pre2), P3 = bpl(aR2, pre3);
    float G2 = bpl(aR2, g);
    return make_float4(suf3 + G1 + P1, suf2 + G1 + P2, v.w + G1 + P3, G1 + G2);
}

// ---------------- prep: raw image -> fp16 centered (ac) + fp16 1/sqrt -----
// One wave per (z, strip, 16-row seg). Strips x0 = {0,232,468}. 32 steps
// (rolled 4x8). FIFO depth 4.
__global__ __launch_bounds__(64, 2) void prep_f4(
    const float* __restrict__ outs, const float* __restrict__ labs,
    __half* __restrict__ ac, __half* __restrict__ rs, float* __restrict__ wsum)
{
    const int l  = threadIdx.x;
    if (blockIdx.x == 0 && blockIdx.y == 0 && blockIdx.z == 0 && l < 24)
        wsum[l * 64] = 0.f;                   // zero per-z partial slots
    const int s  = blockIdx.x;
    const int x0 = (s == 0) ? 0 : (s == 1 ? 232 : 468);
    const int y0 = 16 * blockIdx.y;
    const int z  = blockIdx.z;

    const float* src = (z < 24) ? outs + z * HW : labs + (z - 24) * HW;
    __half* acd = ac + z * HW;
    __half* rsd = rs + z * HW;

    const int   bcol0 = x0 - 4 + 4 * l;
    const int   bcol  = min(max(bcol0, 0), WW - 4);
    const float cmask = (bcol0 >= 0 && bcol0 <= WW - 4) ? 1.f : 0.f;
    const int   ocol0 = x0 + 4 * l;
    const int   aL1 = ((l - 1) & 63) << 2;
    const int   aR1 = ((l + 1) & 63) << 2;
    const int   aR2 = ((l + 2) & 63) << 2;
    const bool stA = (l >= 1 && l <= 60 && bcol0 >= 0 && bcol0 <= WW - 4);
    const bool stS = (l >= ((x0 == 0) ? 0 : 1) && l <= 59 && ocol0 <= WW - 4);

    float4 fifo[4];
    fifo[0] = *(const float4*)&src[rcl(y0 - 7) * WW + bcol];
    fifo[1] = *(const float4*)&src[rcl(y0 - 6) * WW + bcol];
    fifo[2] = *(const float4*)&src[rcl(y0 - 5) * WW + bcol];
    fifo[3] = *(const float4*)&src[rcl(y0 - 4) * WW + bcol];

    float4 araw[4], haR[8], rgS[8];
    float4 VA = make_float4(0,0,0,0), Vq = make_float4(0,0,0,0);
    #pragma unroll
    for (int k = 0; k < 4; ++k) araw[k] = make_float4(0,0,0,0);
    #pragma unroll
    for (int k = 0; k < 8; ++k) { haR[k] = make_float4(0,0,0,0); rgS[k] = make_float4(0,0,0,0); }

    auto step = [&](const int t, const int kk) {
        const int   r  = y0 - 7 + t;
        const float rm = (r >= 0 && r < HH) ? cmask : 0.f;
        float4 raw = fifo[kk & 3];
        float4 av  = make_float4(raw.x*rm, raw.y*rm, raw.z*rm, raw.w*rm);
        if (t <= 26) fifo[kk & 3] = *(const float4*)&src[rcl(r + 4) * WW + bcol];

        float4 h = winC(av, aL1, aR1);
        VA.x += h.x - haR[kk].x; VA.y += h.y - haR[kk].y;
        VA.z += h.z - haR[kk].z; VA.w += h.w - haR[kk].w;
        haR[kk] = h;

        float4 aold = araw[kk & 3]; araw[kk & 3] = av;   // row c = r-4
        const int   c  = r - 4;
        const float cm = (c >= 0 && c < HH) ? cmask : 0.f;
        float4 acv = make_float4((aold.x - VA.x*(1.f/64.f))*cm,
                                 (aold.y - VA.y*(1.f/64.f))*cm,
                                 (aold.z - VA.z*(1.f/64.f))*cm,
                                 (aold.w - VA.w*(1.f/64.f))*cm);
        if (t >= 11 && t <= 26) {
            if (stA) *(uint2*)&acd[c * WW + bcol0] = f2h4(acv);  // c in [y0,y0+15]
        }
        float4 sq = make_float4(acv.x*acv.x, acv.y*acv.y, acv.z*acv.z, acv.w*acv.w);
        Vq.x += sq.x - rgS[kk].x; Vq.y += sq.y - rgS[kk].y;
        Vq.z += sq.z - rgS[kk].z; Vq.w += sq.w - rgS[kk].w;
        rgS[kk] = sq;
        if (t >= 15 && t <= 30) {                        // emit row y = c-4
            const int y = c - 4;                         // y in [y0, y0+15]
            float4 h2 = winR(Vq, aR1, aR2);              // box sum of sq
            float4 rv = make_float4(
                fminf(__frsqrt_rn(fmaxf(h2.x, EPV)), 60000.f),
                fminf(__frsqrt_rn(fmaxf(h2.y, EPV)), 60000.f),
                fminf(__frsqrt_rn(fmaxf(h2.z, EPV)), 60000.f),
                fminf(__frsqrt_rn(fmaxf(h2.w, EPV)), 60000.f));
            if (stS) *(uint2*)&rsd[y * WW + ocol0] = f2h4(rv);
        }
    };
    for (int it = 0; it < 4; ++it) {
        const int t0 = it * 8;
        #pragma unroll
        for (int kk = 0; kk < 8; ++kk) step(t0 + kk, kk);
    }
}

// ---------------- main: product boxes, ring-free sliding sums -------------
// One wave per (z=b*6+i, strip x0={0,240,480}, 8-row seg). 15 steps, fully
// unrolled. 4608 waves = 18/CU resident. XCD-chunked: XCD k owns z in
// {3k,3k+1,3k+2}. All loads are 8B fp16 (port-bound fix).
__global__ __launch_bounds__(64, 2) void ncc_f4(
    const __half* __restrict__ ac, const __half* __restrict__ rs,
    float* __restrict__ wsum)
{
    const int l   = threadIdx.x;
    const int n   = blockIdx.x;            // 0..4607
    const int xcd = n & 7;                 // block n -> XCD n%8 (round-robin)
    const int p   = n >> 3;                // 0..575 within XCD
    const int zq  = p / 192;               // 0..2
    const int rem = p - 192 * zq;          // 0..191
    const int seg = rem / 3;               // 0..63
    const int stp = rem - 3 * seg;         // 0..2
    const int x0  = 240 * stp;
    const int y0  = 8 * seg;
    const int z   = 3 * xcd + zq;          // b*6 + i
    const int b   = z / 6;

    const __half* acp = ac + z * HW;
    const __half* sip = rs + z * HW;
    const __half* bcp[4]; const __half* sjp[4];
    #pragma unroll
    for (int j = 0; j < 4; ++j) {
        bcp[j] = ac + (24 + b * 4 + j) * HW;
        sjp[j] = rs + (24 + b * 4 + j) * HW;
    }

    const int   bcol0 = x0 - 4 + 4 * l;
    const int   bcol  = min(max(bcol0, 0), WW - 4);
    const float cmask = (bcol0 >= 0 && bcol0 <= WW - 4) ? 1.f : 0.f;
    const int   ocol0 = x0 + 4 * l;
    const int   ocol  = min(ocol0, WW - 4);
    const float om    = (l <= 59 && ocol0 <= WW - 4) ? 1.f : 0.f;
    const int   aR1 = ((l + 1) & 63) << 2;
    const int   aR2 = ((l + 2) & 63) << 2;

    uint2 fa[2], fb[4][2];      // "new" rows (add,    2-step slack), fp16 raw
    uint2 faO[2], fbO[4][2];    // "old" rows (subtract, 2-step slack)
    {
        const int r0 = rcl(y0 - 3), r1 = rcl(y0 - 2);
        fa[0]  = *(const uint2*)&acp[r0 * WW + bcol];
        fa[1]  = *(const uint2*)&acp[r1 * WW + bcol];
        faO[0] = fa[0];
        faO[1] = fa[1];
        #pragma unroll
        for (int j = 0; j < 4; ++j) {
            fb[j][0]  = *(const uint2*)&bcp[j][r0 * WW + bcol];
            fb[j][1]  = *(const uint2*)&bcp[j][r1 * WW + bcol];
            fbO[j][0] = fb[j][0];
            fbO[j][1] = fb[j][1];
        }
    }

    float4 Vp[4];
    uint2 psiB[2], psjB[2][4];
    float4 xs = make_float4(0,0,0,0);
    #pragma unroll
    for (int j = 0; j < 4; ++j) Vp[j] = make_float4(0,0,0,0);
    #pragma unroll
    for (int q = 0; q < 2; ++q) {
        psiB[q] = make_uint2(0, 0);
        #pragma unroll
        for (int j = 0; j < 4; ++j) psjB[q][j] = make_uint2(0, 0);
    }

    auto step = [&](const int t, const int kk) {
        const int   c  = y0 - 3 + t;                 // row being ADDED
        const float rm = (c >= 0 && c < HH) ? cmask : 0.f;
        float4 av = h2f4(fa[kk & 1]);
        av = make_float4(av.x*rm, av.y*rm, av.z*rm, av.w*rm);
        float4 bv0 = h2f4(fb[0][kk & 1]), bv1 = h2f4(fb[1][kk & 1]);
        float4 bv2 = h2f4(fb[2][kk & 1]), bv3 = h2f4(fb[3][kk & 1]);
        if (t <= 12) {                               // consumed through t=14
            const int rn = rcl(c + 2);
            fa[kk & 1] = *(const uint2*)&acp[rn * WW + bcol];
            #pragma unroll
            for (int j = 0; j < 4; ++j)
                fb[j][kk & 1] = *(const uint2*)&bcp[j][rn * WW + bcol];
        }
        // add new products
        Vp[0].x += av.x*bv0.x; Vp[0].y += av.y*bv0.y; Vp[0].z += av.z*bv0.z; Vp[0].w += av.w*bv0.w;
        Vp[1].x += av.x*bv1.x; Vp[1].y += av.y*bv1.y; Vp[1].z += av.z*bv1.z; Vp[1].w += av.w*bv1.w;
        Vp[2].x += av.x*bv2.x; Vp[2].y += av.y*bv2.y; Vp[2].z += av.z*bv2.z; Vp[2].w += av.w*bv2.w;
        Vp[3].x += av.x*bv3.x; Vp[3].y += av.y*bv3.y; Vp[3].z += av.z*bv3.z; Vp[3].w += av.w*bv3.w;
        // subtract row c-8 (re-loaded; L1/L2-hot from 8 steps ago)
        if (t >= 8) {
            const int   co  = c - 8;
            const float rmO = (co >= 0) ? cmask : 0.f;
            float4 avO = h2f4(faO[kk & 1]);
            avO = make_float4(avO.x*rmO, avO.y*rmO, avO.z*rmO, avO.w*rmO);
            float4 bo0 = h2f4(fbO[0][kk & 1]), bo1 = h2f4(fbO[1][kk & 1]);
            float4 bo2 = h2f4(fbO[2][kk & 1]), bo3 = h2f4(fbO[3][kk & 1]);
            Vp[0].x -= avO.x*bo0.x; Vp[0].y -= avO.y*bo0.y; Vp[0].z -= avO.z*bo0.z; Vp[0].w -= avO.w*bo0.w;
            Vp[1].x -= avO.x*bo1.x; Vp[1].y -= avO.y*bo1.y; Vp[1].z -= avO.z*bo1.z; Vp[1].w -= avO.w*bo1.w;
            Vp[2].x -= avO.x*bo2.x; Vp[2].y -= avO.y*bo2.y; Vp[2].z -= avO.z*bo2.z; Vp[2].w -= avO.w*bo2.w;
            Vp[3].x -= avO.x*bo3.x; Vp[3].y -= avO.y*bo3.y; Vp[3].z -= avO.z*bo3.z; Vp[3].w -= avO.w*bo3.w;
        }
        if (t >= 6 && t <= 12) {                     // subtract-row prefetch
            const int ro = rcl(c - 6);               // used at t+2 (row c-8)
            faO[kk & 1] = *(const uint2*)&acp[ro * WW + bcol];
            #pragma unroll
            for (int j = 0; j < 4; ++j)
                fbO[j][kk & 1] = *(const uint2*)&bcp[j][ro * WW + bcol];
        }

        if (t >= 7) {
            // emit row y = y0+t-7; psiB[t&1] holds row y (loaded 2 steps ago)
            const int   y  = y0 + t - 7;
            const float em = (y < HH) ? om : 0.f;
            const float4 psi = h2f4(psiB[t & 1]);
            float mmx = -1.f, mmy = -1.f, mmz = -1.f, mmw = -1.f;
            #pragma unroll
            for (int j = 0; j < 4; ++j) {
                float4 hj = winR(Vp[j], aR1, aR2);
                float4 sj = h2f4(psjB[t & 1][j]);
                mmx = fmaxf(mmx, hj.x * (psi.x * sj.x));
                mmy = fmaxf(mmy, hj.y * (psi.y * sj.y));
                mmz = fmaxf(mmz, hj.z * (psi.z * sj.z));
                mmw = fmaxf(mmw, hj.w * (psi.w * sj.w));
            }
            xs.x += em * (1.f - fminf(mmx, 1.f));
            xs.y += em * (1.f - fminf(mmy, 1.f));
            xs.z += em * (1.f - fminf(mmz, 1.f));
            xs.w += em * (1.f - fminf(mmw, 1.f));
        }
        if (t >= 5 && t <= 12) {             // psi prefetch, 2-step slack
            const int yn = min(y0 + t - 5, HH - 1);
            psiB[t & 1] = *(const uint2*)&sip[yn * WW + ocol];
            #pragma unroll
            for (int j = 0; j < 4; ++j)
                psjB[t & 1][j] = *(const uint2*)&sjp[j][yn * WW + ocol];
        }
    };
    #pragma unroll
    for (int t = 0; t < 15; ++t) step(t, t & 7);

    float xt = xs.x + xs.y + xs.z + xs.w;
    #pragma unroll
    for (int off = 32; off > 0; off >>= 1) xt += __shfl_down(xt, off);
    if (l == 0) atomicAdd(&wsum[z * 64], xt);   // per-z line, 192-way only
}

// ---------------- finalize: 24 partials -> 25 outputs ---------------------
__global__ void fin_f4(const float* __restrict__ wsum, float* __restrict__ out)
{
    const int l = threadIdx.x;
    float v = (l < 24) ? wsum[l * 64] : 0.f;
    if (l < 24) out[1 + l] = v * (1.f / (float)HW);
    #pragma unroll
    for (int off = 32; off > 0; off >>= 1) v += __shfl_down(v, off);
    if (l == 0) out[0] = v * (1.f / (24.f * (float)HW));
}

extern "C" void kernel_launch(void* const* d_in, const int* in_sizes, int n_in,
                              void* d_out, int out_size, void* d_ws, size_t ws_size,
                              hipStream_t stream) {
    const float* outs = (const float*)d_in[0];   // (4,6,512,512)
    const float* labs = (const float*)d_in[1];   // (4,4,512,512)
    float* out = (float*)d_out;                  // 25 floats
    float* ws  = (float*)d_ws;

    __half* acw  = (__half*)ws;            // 40*HW halves (a:0..23, b:24..39)
    __half* rsw  = (__half*)ws + 40 * HW;  // 40*HW halves (fp16 1/sqrt(var))
    float*  wsum = ws + 40 * HW;           // floats: after the two half arrays

    // prep: 3 strips x 32 segs(16 rows) x 40 images (also zeroes wsum)
    prep_f4<<<dim3(3, 32, 40), 64, 0, stream>>>(outs, labs, acw, rsw, wsum);
    // main: 4608 blocks, XCD-chunked decode inside the kernel
    ncc_f4<<<dim3(4608, 1, 1), 64, 0, stream>>>(acw, rsw, wsum);
    // finalize: one wave
    fin_f4<<<dim3(1, 1, 1), 64, 0, stream>>>(wsum, out);
}